// Round 3
// baseline (62.904 us; speedup 1.0000x reference)
//
#include <hip/hip_runtime.h>

#define W_IMG 256
#define H_IMG 256
#define NPTS  1024
#define SIG_CUT 15.0f   // skipped gaussians contribute < e^-15 each; 1024*e^-15 ~ 3e-4 << 0.02

// d_ws layout (float4 units):
//   ws[0      .. NPTS-1]      : {cx, cy, rx, ry}     (bbox scan array, SoA-coalesced)
//   ws[NPTS   + 2*i + 0]      : {CA, CB, CC, pad}
//   ws[NPTS   + 2*i + 1]      : {fr, fg, fb, pad}
// total 48 KB of the ~268 MB workspace.

__global__ __launch_bounds__(256) void gsplat_prep(
    const float* __restrict__ xyz,
    const float* __restrict__ chol,
    const float* __restrict__ opac,
    const float* __restrict__ feat,
    float4* __restrict__ ws)
{
    const int i = blockIdx.x * 256 + threadIdx.x;   // 4 blocks x 256 = 1024
    const float LOG2E     = 1.4426950408889634f;
    const float TWO_LOG2E = 2.8853900817779268f;

    float2 xy = ((const float2*)xyz)[i];
    // tanh(x) = 1 - 2/(exp(2x)+1)
    float e0 = exp2f(TWO_LOG2E * xy.x);
    float e1 = exp2f(TWO_LOG2E * xy.y);
    float mx = 1.0f - 2.0f * __builtin_amdgcn_rcpf(e0 + 1.0f);
    float my = 1.0f - 2.0f * __builtin_amdgcn_rcpf(e1 + 1.0f);
    float cx = 0.5f * (float)W_IMG * (mx + 1.0f);
    float cy = 0.5f * (float)H_IMG * (my + 1.0f);

    float l1 = chol[3 * i + 0] + 0.5f;
    float l2 = chol[3 * i + 1];
    float l3 = chol[3 * i + 2] + 0.5f;
    float a = l1 * l1;
    float b = l1 * l2;
    float c = fmaf(l2, l2, l3 * l3);

    // conservative bbox: sigma >= dx^2/(2a), dy^2/(2c)
    float rx = sqrtf(2.0f * SIG_CUT * a);
    float ry = sqrtf(2.0f * SIG_CUT * c);

    float det = fmaf(a, c, -b * b);                 // = l1^2*l3^2 >= 0.0625
    float inv = __builtin_amdgcn_rcpf(det);
    float o = opac[i];

    ws[i] = make_float4(cx, cy, rx, ry);
    // w = exp(-sigma) = exp2(CA*dx^2 + CB*dx*dy + CC*dy^2)
    ws[NPTS + 2 * i + 0] = make_float4(-0.5f * c * inv * LOG2E,
                                        b * inv * LOG2E,
                                        -0.5f * a * inv * LOG2E, 0.0f);
    ws[NPTS + 2 * i + 1] = make_float4(feat[3 * i + 0] * o,
                                       feat[3 * i + 1] * o,
                                       feat[3 * i + 2] * o, 0.0f);
}

// 16x16 px tiles, one block per tile. Scan precomputed bboxes (coalesced
// float4), compact survivors to LDS, then accumulate per pixel.
__global__ __launch_bounds__(256) void gsplat_render(
    const float4* __restrict__ ws,
    float* __restrict__ out)
{
    __shared__ float4 sp4[NPTS * 2];
    __shared__ int scnt;

    const int tid = threadIdx.x;
    const int tx0 = (blockIdx.x & 15) << 4;
    const int ty0 = (blockIdx.x >> 4) << 4;

    if (tid == 0) scnt = 0;
    __syncthreads();

    const float xlo = (float)tx0,      xhi = (float)(tx0 + 16);
    const float ylo = (float)ty0,      yhi = (float)(ty0 + 16);

    #pragma unroll 4
    for (int i = tid; i < NPTS; i += 256) {
        float4 q = ws[i];                 // cx, cy, rx, ry
        bool hit = (q.x >= xlo - q.z) && (q.x <= xhi + q.z) &&
                   (q.y >= ylo - q.w) && (q.y <= yhi + q.w);
        if (hit) {
            float4 qa = ws[NPTS + 2 * i + 0];   // CA, CB, CC, -
            float4 qb = ws[NPTS + 2 * i + 1];   // fr, fg, fb, -
            int slot = atomicAdd(&scnt, 1);
            sp4[2 * slot + 0] = make_float4(q.x, q.y, qa.x, qa.y);
            sp4[2 * slot + 1] = make_float4(qa.z, qb.x, qb.y, qb.z);
        }
    }
    __syncthreads();
    const int n = scnt;

    const int x = tx0 + (tid & 15);
    const int y = ty0 + (tid >> 4);
    const float px = (float)x + 0.5f;
    const float py = (float)y + 0.5f;

    float r = 0.0f, g = 0.0f, bl = 0.0f;
    #pragma unroll 4
    for (int j = 0; j < n; ++j) {
        float4 q0 = sp4[2 * j + 0];   // cx, cy, CA, CB
        float4 q1 = sp4[2 * j + 1];   // CC, fr, fg, fb
        float dx = px - q0.x;
        float dy = py - q0.y;
        float t  = fmaf(q0.z, dx, q0.w * dy);
        float s  = fmaf(dx, t, (q1.x * dy) * dy);
        float w  = exp2f(s);
        r  = fmaf(w, q1.y, r);
        g  = fmaf(w, q1.z, g);
        bl = fmaf(w, q1.w, bl);
    }

    const int p = y * W_IMG + x;
    out[0 * H_IMG * W_IMG + p] = fminf(fmaxf(r,  0.0f), 1.0f);
    out[1 * H_IMG * W_IMG + p] = fminf(fmaxf(g,  0.0f), 1.0f);
    out[2 * H_IMG * W_IMG + p] = fminf(fmaxf(bl, 0.0f), 1.0f);
}

extern "C" void kernel_launch(void* const* d_in, const int* in_sizes, int n_in,
                              void* d_out, int out_size, void* d_ws, size_t ws_size,
                              hipStream_t stream) {
    const float* xyz  = (const float*)d_in[0];
    const float* chol = (const float*)d_in[1];
    const float* opac = (const float*)d_in[2];
    const float* feat = (const float*)d_in[3];
    float* out = (float*)d_out;
    float4* ws = (float4*)d_ws;
    (void)in_sizes; (void)n_in; (void)out_size; (void)ws_size;

    gsplat_prep<<<NPTS / 256, 256, 0, stream>>>(xyz, chol, opac, feat, ws);
    gsplat_render<<<(W_IMG / 16) * (H_IMG / 16), 256, 0, stream>>>(ws, out);
}